// Round 1
// baseline (157.164 us; speedup 1.0000x reference)
//
#include <hip/hip_runtime.h>

#define NWORDS 1024  // 65536 pixels / 64 bits per word

// Find next set bit strictly after global bit position `pos` in cw[0..NWORDS).
__device__ __forceinline__ int next_set(const unsigned long long* cw, int pos) {
    int w = pos >> 6;
    int b = pos & 63;
    unsigned long long m = cw[w];
    m = (b == 63) ? 0ULL : (m & (~0ULL << (b + 1)));
    while (m == 0ULL) {
        ++w;
        if (w >= NWORDS) return -1;
        m = cw[w];
    }
    return (w << 6) + __builtin_ctzll(m);
}

__global__ __launch_bounds__(1024)
void bending_loss_kernel(const float* __restrict__ target, float* __restrict__ out,
                         float inv_b) {
#pragma clang fp contract(off)
    __shared__ unsigned long long bits[NWORDS];   // mask bitmap
    __shared__ unsigned long long cw[NWORDS];     // contour bitmap
    __shared__ float wsum[16];

    const int img_idx = blockIdx.x;
    const int tid  = threadIdx.x;
    const int wave = tid >> 6;
    const int lane = tid & 63;

    // channel 1 plane of image img_idx: target[img_idx, 1, :, :]
    const float* img = target + (size_t)img_idx * 131072 + 65536;

    // ---- Phase 1: mask bitmap. Word k covers pixels [k*64, k*64+64). ----
    for (int k = wave; k < NWORDS; k += 16) {
        float v = img[(k << 6) + lane];
        unsigned long long bal = __ballot(v > 0.5f);
        if (lane == 0) bits[k] = bal;
    }
    __syncthreads();

    // ---- Phase 2: contour words. Row r has 4 words (256 cols). ----
    {
        const int k = tid;
        const int r = k >> 2, wp = k & 3;
        auto get = [&](int rr, int ww) -> unsigned long long {
            return (rr < 0 || rr > 255 || ww < 0 || ww > 3)
                       ? 0ULL : bits[(rr << 2) + ww];
        };
        unsigned long long A  = get(r - 1, wp);
        unsigned long long C  = bits[k];
        unsigned long long B  = get(r + 1, wp);
        unsigned long long Ap = get(r - 1, wp - 1), An = get(r - 1, wp + 1);
        unsigned long long Cp = get(r,     wp - 1), Cn = get(r,     wp + 1);
        unsigned long long Bp = get(r + 1, wp - 1), Bn = get(r + 1, wp + 1);
        // west(x) = mask of "neighbor at col-1 set", east(x) = col+1 set.
        unsigned long long interior =
            ((A << 1) | (Ap >> 63)) & A & ((A >> 1) | (An << 63)) &
            ((C << 1) | (Cp >> 63)) &     ((C >> 1) | (Cn << 63)) &
            ((B << 1) | (Bp >> 63)) & B & ((B >> 1) | (Bn << 63));
        cw[k] = C & ~interior;
    }
    __syncthreads();

    // ---- Phase 3: consecutive-triple bending energy. ----
    // Thread k owns triples whose FIRST point lies in word k.
    float sum = 0.0f;
    {
        unsigned long long my = cw[tid];
        if (my) {
            int p0 = (tid << 6) + __builtin_ctzll(my);
            const int lim = (tid + 1) << 6;
            int p1 = next_set(cw, p0);
            int p2 = (p1 >= 0) ? next_set(cw, p1) : -1;
            while (p0 < lim && p2 >= 0) {
                float r0 = (float)(p0 >> 8), c0 = (float)(p0 & 255);
                float r1 = (float)(p1 >> 8), c1 = (float)(p1 & 255);
                float r2 = (float)(p2 >> 8), c2 = (float)(p2 & 255);
                float v1r = r1 - r0, v1c = c1 - c0;
                float v2r = r2 - r1, v2c = c2 - c1;
                float cross = v1r * v2c - v1c * v2r;   // exact (small ints)
                if (cross != 0.0f) {
                    float dot = v1r * v2r + v1c * v2c; // exact
                    float n1 = sqrtf(v1r * v1r + v1c * v1c);
                    float n2 = sqrtf(v2r * v2r + v2c * v2c);
                    float curv = (2.0f * fabsf(cross)) / (n1 * n2 + dot);
                    float factor = (cross >= 0.0f) ? 1.0f : 0.75f; // MU = 0.75
                    sum += (factor * (curv * curv)) / (n1 + n2);
                }
                p0 = p1; p1 = p2;
                p2 = next_set(cw, p2);
            }
        }
    }

    // ---- Phase 4: reduction ----
    for (int off = 32; off > 0; off >>= 1) sum += __shfl_down(sum, off);
    if (lane == 0) wsum[wave] = sum;
    __syncthreads();
    if (tid == 0) {
        float t = 0.0f;
        for (int i = 0; i < 16; ++i) t += wsum[i];
        atomicAdd(out, t * inv_b);
    }
}

extern "C" void kernel_launch(void* const* d_in, const int* in_sizes, int n_in,
                              void* d_out, int out_size, void* d_ws, size_t ws_size,
                              hipStream_t stream) {
    // d_in[0] = input (unused except for B), d_in[1] = target, both (B,2,256,256) f32
    const float* target = (const float*)d_in[1];
    float* out = (float*)d_out;
    const int B = in_sizes[1] / (2 * 256 * 256);

    hipMemsetAsync(out, 0, sizeof(float) * out_size, stream);
    bending_loss_kernel<<<dim3(B), dim3(1024), 0, stream>>>(target, out, 1.0f / (float)B);
}

// Round 2
// 150.951 us; speedup vs baseline: 1.0412x; 1.0412x over previous
//
#include <hip/hip_runtime.h>

#define NW 1024          // 64-bit words per image bitmap (256*256/64)
#define BANDROWS 32
#define NBANDS 8         // 256 / BANDROWS
#define NSEG 8           // stage-2 segments per image

// Find next set bit strictly after global bit position `pos` in cw[0..NW).
__device__ __forceinline__ int next_set(const unsigned long long* cw, int pos) {
    int w = pos >> 6;
    int b = pos & 63;
    unsigned long long m = cw[w];
    m = (b == 63) ? 0ULL : (m & (~0ULL << (b + 1)));
    while (m == 0ULL) {
        ++w;
        if (w >= NW) return -1;
        m = cw[w];
    }
    return (w << 6) + __builtin_ctzll(m);
}

// ---------- Stage 1: mask ballot + contour bit-ops, banded ----------
__global__ __launch_bounds__(1024)
void contour_build_kernel(const float* __restrict__ target,
                          unsigned long long* __restrict__ cwg) {
    __shared__ unsigned long long lb[(BANDROWS + 2) * 4];  // 34 rows x 4 words

    const int img  = blockIdx.x;
    const int band = blockIdx.y;
    const int tid  = threadIdx.x;
    const int wave = tid >> 6, lane = tid & 63;

    const float* imgp = target + (size_t)img * 131072 + 65536; // channel 1 plane
    const int r0 = band * BANDROWS - 1;  // global row of halo row 0

    // Load 34 rows x 4 words; out-of-image rows -> 0 (zero padding semantics).
    for (int w = wave; w < (BANDROWS + 2) * 4; w += 16) {
        const int gr = r0 + (w >> 2);
        unsigned long long bal = 0ULL;
        if (gr >= 0 && gr <= 255) {
            float v = imgp[(gr << 8) + ((w & 3) << 6) + lane];
            bal = __ballot(v > 0.5f);
        }
        if (lane == 0) lb[w] = bal;
    }
    __syncthreads();

    // Contour for the 32 owned rows = 128 words.
    if (tid < BANDROWS * 4) {
        const int k  = tid;
        const int lr = 1 + (k >> 2);   // local row in lb (1..32)
        const int wp = k & 3;
        auto get = [&](int rr, int ww) -> unsigned long long {
            return (ww < 0 || ww > 3) ? 0ULL : lb[(rr << 2) + ww];
        };
        unsigned long long A  = get(lr - 1, wp);
        unsigned long long C  = lb[(lr << 2) + wp];
        unsigned long long Bx = get(lr + 1, wp);
        unsigned long long Ap = get(lr - 1, wp - 1), An = get(lr - 1, wp + 1);
        unsigned long long Cp = get(lr,     wp - 1), Cn = get(lr,     wp + 1);
        unsigned long long Bp = get(lr + 1, wp - 1), Bn = get(lr + 1, wp + 1);
        unsigned long long interior =
            ((A  << 1) | (Ap >> 63)) & A  & ((A  >> 1) | (An << 63)) &
            ((C  << 1) | (Cp >> 63)) &      ((C  >> 1) | (Cn << 63)) &
            ((Bx << 1) | (Bp >> 63)) & Bx & ((Bx >> 1) | (Bn << 63));
        cwg[(size_t)img * NW + band * (BANDROWS * 4) + k] = C & ~interior;
    }
}

// ---------- Stage 2: consecutive-triple bending energy ----------
__global__ __launch_bounds__(1024)
void bending_energy_kernel(const unsigned long long* __restrict__ cwg,
                           float* __restrict__ out, float inv_b) {
#pragma clang fp contract(off)
    __shared__ unsigned long long cw[NW];
    __shared__ float wsum[16];

    const int img = blockIdx.x;
    const int seg = blockIdx.y;
    const int tid = threadIdx.x;
    const int wave = tid >> 6, lane = tid & 63;

    cw[tid] = cwg[(size_t)img * NW + tid];
    __syncthreads();

    float sum = 0.0f;
    // Thread owns the 8-bit chunk `chunk` of the image bitmap (8192 bytes).
    const int chunk = seg * 1024 + tid;
    const int word = chunk >> 3, sh = (chunk & 7) << 3;
    const unsigned int byte = (unsigned int)((cw[word] >> sh) & 0xFFULL);
    if (byte) {
        int p0 = (chunk << 3) + __builtin_ctz(byte);
        const int lim = (chunk + 1) << 3;
        int p1 = next_set(cw, p0);
        int p2 = (p1 >= 0) ? next_set(cw, p1) : -1;
        while (p0 < lim && p2 >= 0) {
            float r0f = (float)(p0 >> 8), c0f = (float)(p0 & 255);
            float r1f = (float)(p1 >> 8), c1f = (float)(p1 & 255);
            float r2f = (float)(p2 >> 8), c2f = (float)(p2 & 255);
            float v1r = r1f - r0f, v1c = c1f - c0f;
            float v2r = r2f - r1f, v2c = c2f - c1f;
            float cross = v1r * v2c - v1c * v2r;   // exact (small ints)
            if (cross != 0.0f) {
                float dot = v1r * v2r + v1c * v2c; // exact
                float n1 = sqrtf(v1r * v1r + v1c * v1c);
                float n2 = sqrtf(v2r * v2r + v2c * v2c);
                float curv = (2.0f * fabsf(cross)) / (n1 * n2 + dot);
                float factor = (cross >= 0.0f) ? 1.0f : 0.75f; // MU
                sum += (factor * (curv * curv)) / (n1 + n2);
            }
            p0 = p1; p1 = p2;
            p2 = next_set(cw, p2);
        }
    }

    for (int off = 32; off > 0; off >>= 1) sum += __shfl_down(sum, off);
    if (lane == 0) wsum[wave] = sum;
    __syncthreads();
    if (tid == 0) {
        float t = 0.0f;
        for (int i = 0; i < 16; ++i) t += wsum[i];
        atomicAdd(out, t * inv_b);
    }
}

extern "C" void kernel_launch(void* const* d_in, const int* in_sizes, int n_in,
                              void* d_out, int out_size, void* d_ws, size_t ws_size,
                              hipStream_t stream) {
    const float* target = (const float*)d_in[1];
    float* out = (float*)d_out;
    const int B = in_sizes[1] / (2 * 256 * 256);
    unsigned long long* cwg = (unsigned long long*)d_ws; // B * 1024 * 8 bytes = 1 MB

    hipMemsetAsync(out, 0, sizeof(float) * out_size, stream);
    contour_build_kernel<<<dim3(B, NBANDS), dim3(1024), 0, stream>>>(target, cwg);
    bending_energy_kernel<<<dim3(B, NSEG), dim3(1024), 0, stream>>>(cwg, out, 1.0f / (float)B);
}